// Round 7
// baseline (777.093 us; speedup 1.0000x reference)
//
#include <hip/hip_runtime.h>
#include <hip/hip_bf16.h>
#include <math.h>

#define NB 16384
#define NH 16
#define ND 256
#define NM 1024
#define BM 128           // rows per block
#define MB 64            // m-chunk
#define NCH (NM / MB)    // 16

typedef float f32x4 __attribute__((ext_vector_type(4)));
typedef float f32x16 __attribute__((ext_vector_type(16)));
typedef short bf16x8 __attribute__((ext_vector_type(8)));
typedef unsigned short u16;
typedef unsigned int u32;

__device__ __forceinline__ u16 f2bf(float f) {
  union { float f; unsigned u; } v; v.f = f;
  unsigned r = v.u + 0x7FFFu + ((v.u >> 16) & 1u);
  return (u16)(r >> 16);
}

// dst[h][c][r] = bf16(src[h][r][c]); src is [16][R][C] fp32.
__global__ __launch_bounds__(256) void transpose_cvt(const float* __restrict__ src,
                                                     u16* __restrict__ dst,
                                                     int R, int C) {
  __shared__ float tile[64][65];
  const int h = blockIdx.z;
  const int r0 = blockIdx.y * 64, c0 = blockIdx.x * 64;
  const int tr = threadIdx.x >> 6;   // 0..3
  const int tc = threadIdx.x & 63;
  const float* s = src + (size_t)h * R * C;
#pragma unroll
  for (int i = 0; i < 16; ++i) {
    int r = i * 4 + tr;
    tile[r][tc] = s[(size_t)(r0 + r) * C + (c0 + tc)];
  }
  __syncthreads();
  u16* d = dst + ((size_t)h * C + c0) * R + r0;
#pragma unroll
  for (int i = 0; i < 16; ++i) {
    int c = i * 4 + tr;
    d[(size_t)c * R + tc] = f2bf(tile[tc][c]);
  }
}

// xp[b][i] = bf16(x[b][perm[i]])
__global__ __launch_bounds__(1024) void permute_x(const float* __restrict__ x,
                                                  const int* __restrict__ perm,
                                                  u16* __restrict__ xp) {
  const int b = blockIdx.x;
  const int t = threadIdx.x;
  const float* xr = x + (size_t)b * 4096;
  int4 p = *(const int4*)(perm + t * 4);
  ushort4 o;
  o.x = f2bf(xr[p.x]); o.y = f2bf(xr[p.y]);
  o.z = f2bf(xr[p.z]); o.w = f2bf(xr[p.w]);
  *(ushort4*)(xp + (size_t)b * 4096 + t * 4) = o;
}

// out[b][j] = out[b][unperm[j]] (in place, one row per block)
__global__ __launch_bounds__(1024) void unpermute_out(float* __restrict__ out,
                                                      const int* __restrict__ unperm) {
  __shared__ float row[4096];
  const int b = blockIdx.x;
  const int t = threadIdx.x;
  float* orow = out + (size_t)b * 4096;
  *(f32x4*)(row + t * 4) = *(const f32x4*)(orow + t * 4);
  __syncthreads();
  int4 u = *(const int4*)(unperm + t * 4);
  f32x4 v;
  v.x = row[u.x]; v.y = row[u.y]; v.z = row[u.z]; v.w = row[u.w];
  *(f32x4*)(orow + t * 4) = v;
}

// 8-wave (512-thread) MLP with 32x32x16 MFMA (2x FLOP per LDS byte vs
// 16x16x32) and FRAGMENT-ORDER LDS layouts [kh][row][16B granule]
// (kh = kstep*2 + lanehalf): every ds_read_b128 / Ps ds_write_b64 is
// linear across lanes -> zero bank conflicts by construction. gload_lds
// keeps its linear LDS dest; the layout permutation is applied to the
// per-lane GLOBAL source address instead (weights are L2-hot, so the
// 512B/2048B-strided 16B gathers are cheap).
//  phase A (swapped): rt=w&3 (32 rows), mt=w>>2 (32 m). 16 Us reads ->
//    16 MFMAs; C = P^T: lane holds 4x4 consecutive m for one x-row ->
//    4x cvt_pk-packed ds_write_b64.
//  phase B: rtp=w&1 (64-row half), dq=w>>1 (64-d quarter). Per ks: 2 Ps
//    A-frags + 2 Ds B-frags (each reused x2) -> 16 MFMAs, 16 reads.
// VGPR: xr 64 + ca 64 + pa 16 + temps ~= 190 -> launch_bounds(512,2)
// (cap 256). 144KB LDS -> 1 block/CU, 2 waves/SIMD.
__global__ __launch_bounds__(512, 2) void mlp_fused(
    const u16* __restrict__ xp,
    const u16* __restrict__ upT,
    const u16* __restrict__ downT,
    float* __restrict__ out) {
  __shared__ __align__(16) u16 Us[2][MB * ND];   // 2x32KB [kh32][m64][8]
  __shared__ __align__(16) u16 Ds[2][ND * MB];   // 2x32KB [kh8][d256][8]
  __shared__ __align__(16) u16 Ps[BM * MB];      // 16KB   [kh8][r128][8]

  const int h   = blockIdx.y;
  const int rb  = blockIdx.x;
  const int tid = threadIdx.x;
  const int w   = tid >> 6;
  const int l   = tid & 63;
  const int lo  = l & 31;
  const int hi  = l >> 5;
  // phase-A mapping
  const int rtA = w & 3;      // 32-row tile
  const int mt  = w >> 2;     // 32-m tile of the 64-m chunk
  // phase-B mapping
  const int rtp = w & 1;      // 64-row half
  const int dq  = w >> 1;     // 64-d quarter
  const int row0 = rb * BM;

  const char* upH = (const char*)(upT + (size_t)h * NM * ND);
  const char* dnH = (const char*)(downT + (size_t)h * ND * NM);

  // ---- X fragments: phase-A B-operand. Lane = x-row (rtA*32+lo),
  //      k = ks*16 + hi*8 + e. 16 x b128 = 64 VGPR.
  bf16x8 xr[16];
  {
    const char* px = (const char*)(xp + (size_t)(row0 + rtA * 32 + lo) * 4096 + h * ND);
#pragma unroll
    for (int ks = 0; ks < 16; ++ks)
      xr[ks] = *(const bf16x8*)(px + ks * 32 + hi * 16);
  }

  // ---- stage Up chunk 32KB into [kh32][m64][16B]: granule t=(kh*64+m),
  //      src = upT row (mc*64+m), d-bytes kh*16.
  auto stage_us = [&](int mc, int buf) {
#pragma unroll
    for (int i = 0; i < 4; ++i) {
      int t = i * 512 + tid;
      int m = t & 63, kh = t >> 6;
      const char* src = upH + (size_t)(mc * MB + m) * 512 + kh * 16;
      __builtin_amdgcn_global_load_lds(
          (const __attribute__((address_space(1))) void*)src,
          (__attribute__((address_space(3))) void*)((char*)&Us[buf][0] + (size_t)t * 16),
          16, 0, 0);
    }
  };
  // ---- stage Down chunk 32KB into [kh8][d256][16B]: granule t=(kh*256+d),
  //      src = downT row d, m-bytes mc*128 + kh*16.
  auto stage_ds = [&](int mc, int buf) {
#pragma unroll
    for (int i = 0; i < 4; ++i) {
      int t = i * 512 + tid;
      int d = t & 255, kh = t >> 8;
      const char* src = dnH + (size_t)d * 2048 + mc * 128 + kh * 16;
      __builtin_amdgcn_global_load_lds(
          (const __attribute__((address_space(1))) void*)src,
          (__attribute__((address_space(3))) void*)((char*)&Ds[buf][0] + (size_t)t * 16),
          16, 0, 0);
    }
  };

  f32x16 ca[2][2];   // [rt2][dt] 32x32 tiles: 64 rows x 64 d -> 64 VGPR
#pragma unroll
  for (int rt2 = 0; rt2 < 2; ++rt2)
#pragma unroll
    for (int dt = 0; dt < 2; ++dt)
#pragma unroll
      for (int e = 0; e < 16; ++e)
        ca[rt2][dt][e] = 0.f;

  stage_us(0, 0);
  stage_ds(0, 0);
  __syncthreads();   // chunk-0 tiles ready

  // Ps write base: row r = rtA*32+lo, elem slot hi*8; + (mt*4+g)*2048 per g.
  char* const psW = (char*)Ps + (size_t)(rtA * 32 + lo) * 16 + hi * 8;
  const char* const psB = (const char*)Ps;

  for (int mc = 0; mc < NCH; ++mc) {
    const int cur = mc & 1;
    // Only VMEM in the loop -> stays in flight across barrier1 (lgkm-only),
    // drained at barrier2 after a full chunk of cover.
    if (mc + 1 < NCH) {
      stage_us(mc + 1, cur ^ 1);
      stage_ds(mc + 1, cur ^ 1);
    }

    // ---- phase A (swapped): P^T[32m x 32r] = Up-frags @ X-frags
    //      A-frag: lane = m-row (mt*32+lo), k = ks*16+hi*8+e -> granule
    //      (ks*2+hi)*1024 + m*16 : lanes linear, conflict-free.
    f32x16 pa;
#pragma unroll
    for (int e = 0; e < 16; ++e) pa[e] = 0.f;
    {
      const char* ub = (const char*)&Us[cur][0] + (size_t)(mt * 32 + lo) * 16 + hi * 1024;
      __builtin_amdgcn_s_setprio(1);
#pragma unroll
      for (int ks = 0; ks < 16; ++ks) {
        bf16x8 av = *(const bf16x8*)(ub + ks * 2048);
        pa = __builtin_amdgcn_mfma_f32_32x32x16_bf16(av, xr[ks], pa, 0, 0, 0);
      }
      __builtin_amdgcn_s_setprio(0);
    }

    // ---- gelu -> pack -> 4x ds_write_b64 (conflict-free linear)
    // pa[4g+e] = P[r=rtA*32+lo][m = mt*32 + g*8 + hi*4 + e]
#pragma unroll
    for (int g = 0; g < 4; ++g) {
      float gv[4];
#pragma unroll
      for (int e = 0; e < 4; ++e) {
        float v = pa[g * 4 + e];
        float p = __builtin_fmaf(0.1029433f, v * v, 2.3022082f);
        float ex = __builtin_amdgcn_exp2f(v * p);
        float r = __builtin_amdgcn_rcpf(ex + 1.0f);
        gv[e] = __builtin_fmaf(-v, r, v);
      }
      u32 w0, w1;
      asm("v_cvt_pk_bf16_f32 %0, %1, %2" : "=v"(w0) : "v"(gv[0]), "v"(gv[1]));
      asm("v_cvt_pk_bf16_f32 %0, %1, %2" : "=v"(w1) : "v"(gv[2]), "v"(gv[3]));
      uint2 pk; pk.x = w0; pk.y = w1;
      *(uint2*)(psW + (size_t)(mt * 4 + g) * 2048) = pk;
    }

    // barrier1: Ps handoff (DS only); staged loads NOT drained here
    __builtin_amdgcn_sched_barrier(0);
    asm volatile("s_waitcnt lgkmcnt(0)" ::: "memory");
    __builtin_amdgcn_s_barrier();
    __builtin_amdgcn_sched_barrier(0);

    // ---- phase B: C[64r x 64d] += Ps @ Down. Per ks: 2 A-frags (Ps) +
    //      2 B-frags (Ds, each reused x2) -> 4 MFMAs. All reads linear.
    {
      const char* dsb = (const char*)&Ds[cur][0];
      __builtin_amdgcn_s_setprio(1);
#pragma unroll
      for (int ks = 0; ks < 4; ++ks) {
        const size_t khp = (size_t)(ks * 2 + hi);
        bf16x8 a0 = *(const bf16x8*)(psB + khp * 2048 + (size_t)(rtp * 64 + lo) * 16);
        bf16x8 a1 = *(const bf16x8*)(psB + khp * 2048 + (size_t)(rtp * 64 + 32 + lo) * 16);
#pragma unroll
        for (int dt = 0; dt < 2; ++dt) {
          bf16x8 bv = *(const bf16x8*)(dsb + khp * 4096 + (size_t)(dq * 64 + dt * 32 + lo) * 16);
          ca[0][dt] = __builtin_amdgcn_mfma_f32_32x32x16_bf16(a0, bv, ca[0][dt], 0, 0, 0);
          ca[1][dt] = __builtin_amdgcn_mfma_f32_32x32x16_bf16(a1, bv, ca[1][dt], 0, 0, 0);
        }
      }
      __builtin_amdgcn_s_setprio(0);
    }

    // barrier2: Ps reads done; staged tiles landed (full-chunk cover)
    __syncthreads();
  }

  // ---- epilogue: out[b][h*256+d], coalesced across lanes (32 consecutive d)
  // C-layout 32x32: col d = lo, row = (reg&3) + 8*(reg>>2) + 4*hi.
  {
#pragma unroll
    for (int rt2 = 0; rt2 < 2; ++rt2)
#pragma unroll
      for (int dt = 0; dt < 2; ++dt) {
        const int d = h * ND + dq * 64 + dt * 32 + lo;
#pragma unroll
        for (int reg = 0; reg < 16; ++reg) {
          int r = rtp * 64 + rt2 * 32 + (reg & 3) + 8 * (reg >> 2) + 4 * hi;
          out[(size_t)(row0 + r) * 4096 + d] = ca[rt2][dt][reg];
        }
      }
  }
}

extern "C" void kernel_launch(void* const* d_in, const int* in_sizes, int n_in,
                              void* d_out, int out_size, void* d_ws, size_t ws_size,
                              hipStream_t stream) {
  const float* x    = (const float*)d_in[0];
  const float* up   = (const float*)d_in[1];
  const float* down = (const float*)d_in[2];
  const int* perm   = (const int*)d_in[3];
  const int* unperm = (const int*)d_in[4];
  float* out = (float*)d_out;

  u16* upT   = (u16*)d_ws;                                   // 8 MB
  u16* downT = upT + (size_t)NH * NM * ND;                   // 8 MB
  u16* xp    = downT + (size_t)NH * NM * ND;                 // 128 MB

  // upT[h][m][d] <- up[h][d][m]   (R=256 d, C=1024 m)
  transpose_cvt<<<dim3(NM / 64, ND / 64, NH), 256, 0, stream>>>(up, upT, ND, NM);
  // downT[h][d][m] <- down[h][m][d] (R=1024 m, C=256 d)
  transpose_cvt<<<dim3(ND / 64, NM / 64, NH), 256, 0, stream>>>(down, downT, NM, ND);
  // xp[b][i] = bf16(x[b][perm[i]])
  permute_x<<<NB, 1024, 0, stream>>>(x, perm, xp);
  // main fused MLP: 512 thr, 32x32x16 MFMA, fragment-order LDS, 144KB/CU.
  mlp_fused<<<dim3(NB / BM, NH), 512, 0, stream>>>(xp, upT, downT, out);
  // in-place feature unpermute
  unpermute_out<<<NB, 1024, 0, stream>>>(out, unperm);
}

// Round 8
// 623.756 us; speedup vs baseline: 1.2458x; 1.2458x over previous
//
#include <hip/hip_runtime.h>
#include <hip/hip_bf16.h>
#include <math.h>

#define NB 16384
#define NH 16
#define ND 256
#define NM 1024
#define BM 128           // rows per block
#define MB 64            // m-chunk
#define NCH (NM / MB)    // 16

typedef float f32x4 __attribute__((ext_vector_type(4)));
typedef float f32x16 __attribute__((ext_vector_type(16)));
typedef short bf16x8 __attribute__((ext_vector_type(8)));
typedef unsigned short u16;
typedef unsigned int u32;

__device__ __forceinline__ u16 f2bf(float f) {
  union { float f; unsigned u; } v; v.f = f;
  unsigned r = v.u + 0x7FFFu + ((v.u >> 16) & 1u);
  return (u16)(r >> 16);
}

// UpF[h]: granule byte off = mc*32768 + kh*1024 + m*16, kh in [0,32), m in [0,64)
//   elems e: up[h][kh*8+e][mc*64+m]   (up fp32 [H][256][1024])
__global__ __launch_bounds__(256) void prep_up(const float* __restrict__ src,
                                               u16* __restrict__ dst) {
  __shared__ float tile[64][65];
  const int h = blockIdx.z;
  const int m0 = blockIdx.x * 64, d0 = blockIdx.y * 64;
  const int tr = threadIdx.x >> 6, tc = threadIdx.x & 63;
  const float* s = src + (size_t)h * ND * NM;
#pragma unroll
  for (int i = 0; i < 16; ++i) {
    int r = i * 4 + tr;
    tile[r][tc] = s[(size_t)(d0 + r) * NM + m0 + tc];
  }
  __syncthreads();
  char* dh = (char*)dst + (size_t)h * NM * ND * 2;
#pragma unroll
  for (int g = 0; g < 2; ++g) {
    int gi = g * 256 + threadIdx.x;
    int kh_l = gi >> 6, m_l = gi & 63;
    bf16x8 o;
#pragma unroll
    for (int e = 0; e < 8; ++e) o[e] = (short)f2bf(tile[kh_l * 8 + e][m_l]);
    *(bf16x8*)(dh + (size_t)(m0 >> 6) * 32768 + (size_t)((d0 >> 3) + kh_l) * 1024 + m_l * 16) = o;
  }
}

// DownF[h]: granule byte off = mc*32768 + kh*4096 + d*16, kh in [0,8), d in [0,256)
//   elems e: down[h][mc*64+kh*8+e][d]   (down fp32 [H][1024][256])
__global__ __launch_bounds__(256) void prep_down(const float* __restrict__ src,
                                                 u16* __restrict__ dst) {
  __shared__ float tile[64][65];
  const int h = blockIdx.z;
  const int mc = blockIdx.x, d0 = blockIdx.y * 64;
  const int tr = threadIdx.x >> 6, tc = threadIdx.x & 63;
  const float* s = src + (size_t)h * NM * ND;
#pragma unroll
  for (int i = 0; i < 16; ++i) {
    int r = i * 4 + tr;
    tile[r][tc] = s[(size_t)(mc * 64 + r) * ND + d0 + tc];
  }
  __syncthreads();
  char* dh = (char*)dst + (size_t)h * NM * ND * 2;
#pragma unroll
  for (int g = 0; g < 2; ++g) {
    int gi = g * 256 + threadIdx.x;
    int kh_l = gi >> 6, d_l = gi & 63;
    bf16x8 o;
#pragma unroll
    for (int e = 0; e < 8; ++e) o[e] = (short)f2bf(tile[kh_l * 8 + e][d_l]);
    *(bf16x8*)(dh + (size_t)mc * 32768 + (size_t)kh_l * 4096 + (size_t)(d0 + d_l) * 16) = o;
  }
}

// xp[b][i] = bf16(x[b][perm[i]])
__global__ __launch_bounds__(1024) void permute_x(const float* __restrict__ x,
                                                  const int* __restrict__ perm,
                                                  u16* __restrict__ xp) {
  const int b = blockIdx.x;
  const int t = threadIdx.x;
  const float* xr = x + (size_t)b * 4096;
  int4 p = *(const int4*)(perm + t * 4);
  ushort4 o;
  o.x = f2bf(xr[p.x]); o.y = f2bf(xr[p.y]);
  o.z = f2bf(xr[p.z]); o.w = f2bf(xr[p.w]);
  *(ushort4*)(xp + (size_t)b * 4096 + t * 4) = o;
}

// out[b][j] = out[b][unperm[j]] (in place, one row per block)
__global__ __launch_bounds__(1024) void unpermute_out(float* __restrict__ out,
                                                      const int* __restrict__ unperm) {
  __shared__ float row[4096];
  const int b = blockIdx.x;
  const int t = threadIdx.x;
  float* orow = out + (size_t)b * 4096;
  *(f32x4*)(row + t * 4) = *(const f32x4*)(orow + t * 4);
  __syncthreads();
  int4 u = *(const int4*)(unperm + t * 4);
  f32x4 v;
  v.x = row[u.x]; v.y = row[u.y]; v.z = row[u.z]; v.w = row[u.w];
  *(f32x4*)(orow + t * 4) = v;
}

// 8-wave MLP, 32x32x16 MFMA, fragment-order LDS (R7, conflicts 37.7M->4.2M)
// + R8 fixes for R7's stall-bound regression:
//  (1) weights pre-transformed to fragment-granule order on HBM (prep_up/
//      prep_down) -> staging is a LINEAR memcpy: 16 cache lines per
//      global_load_lds wave-inst instead of 64 (R7's 512B/2048B-strided
//      gathers serialized ~64 L1-line-cycles each, ~5K cy/chunk).
//  (2) phase-A accumulator split pa[4] (ks&3) -> dep chains of 4 (~issue-
//      limited) instead of one serial 16-chain (~500 cy exposed at only
//      2 waves/SIMD).
__global__ __launch_bounds__(512, 2) void mlp_fused(
    const u16* __restrict__ xp,
    const u16* __restrict__ upF,
    const u16* __restrict__ downF,
    float* __restrict__ out) {
  __shared__ __align__(16) u16 Us[2][MB * ND];   // 2x32KB [kh32][m64][8]
  __shared__ __align__(16) u16 Ds[2][ND * MB];   // 2x32KB [kh8][d256][8]
  __shared__ __align__(16) u16 Ps[BM * MB];      // 16KB   [kh8][r128][8]

  const int h   = blockIdx.y;
  const int rb  = blockIdx.x;
  const int tid = threadIdx.x;
  const int w   = tid >> 6;
  const int l   = tid & 63;
  const int lo  = l & 31;
  const int hi  = l >> 5;
  // phase-A mapping
  const int rtA = w & 3;      // 32-row tile
  const int mt  = w >> 2;     // 32-m tile of the 64-m chunk
  // phase-B mapping
  const int rtp = w & 1;      // 64-row half
  const int dq  = w >> 1;     // 64-d quarter
  const int row0 = rb * BM;

  const char* upH = (const char*)upF + (size_t)h * NM * ND * 2;
  const char* dnH = (const char*)downF + (size_t)h * NM * ND * 2;

  // ---- X fragments: phase-A B-operand. Lane = x-row (rtA*32+lo),
  //      k = ks*16 + hi*8 + e. 16 x b128 = 64 VGPR. (once per block)
  bf16x8 xr[16];
  {
    const char* px = (const char*)(xp + (size_t)(row0 + rtA * 32 + lo) * 4096 + h * ND);
#pragma unroll
    for (int ks = 0; ks < 16; ++ks)
      xr[ks] = *(const bf16x8*)(px + ks * 32 + hi * 16);
  }

  // ---- stage Up chunk 32KB: pure linear copy (fragment order on HBM)
  auto stage_us = [&](int mc, int buf) {
    const char* src = upH + (size_t)mc * 32768;
#pragma unroll
    for (int i = 0; i < 4; ++i) {
      int t = i * 512 + tid;
      __builtin_amdgcn_global_load_lds(
          (const __attribute__((address_space(1))) void*)(src + (size_t)t * 16),
          (__attribute__((address_space(3))) void*)((char*)&Us[buf][0] + (size_t)t * 16),
          16, 0, 0);
    }
  };
  // ---- stage Down chunk 32KB: pure linear copy
  auto stage_ds = [&](int mc, int buf) {
    const char* src = dnH + (size_t)mc * 32768;
#pragma unroll
    for (int i = 0; i < 4; ++i) {
      int t = i * 512 + tid;
      __builtin_amdgcn_global_load_lds(
          (const __attribute__((address_space(1))) void*)(src + (size_t)t * 16),
          (__attribute__((address_space(3))) void*)((char*)&Ds[buf][0] + (size_t)t * 16),
          16, 0, 0);
    }
  };

  f32x16 ca[2][2];   // [rt2][dt] 32x32 tiles: 64 rows x 64 d -> 64 VGPR
#pragma unroll
  for (int rt2 = 0; rt2 < 2; ++rt2)
#pragma unroll
    for (int dt = 0; dt < 2; ++dt)
#pragma unroll
      for (int e = 0; e < 16; ++e)
        ca[rt2][dt][e] = 0.f;

  stage_us(0, 0);
  stage_ds(0, 0);
  __syncthreads();   // chunk-0 tiles ready

  // Ps write base: row r = rtA*32+lo, elem slot hi*8; + (mt*4+g)*2048 per g.
  char* const psW = (char*)Ps + (size_t)(rtA * 32 + lo) * 16 + hi * 8;
  const char* const psB = (const char*)Ps;

  for (int mc = 0; mc < NCH; ++mc) {
    const int cur = mc & 1;
    // Only VMEM in the loop -> stays in flight across barrier1 (lgkm-only),
    // drained at barrier2 after a full chunk of cover.
    if (mc + 1 < NCH) {
      stage_us(mc + 1, cur ^ 1);
      stage_ds(mc + 1, cur ^ 1);
    }

    // ---- phase A (swapped): P^T[32m x 32r] = Up-frags @ X-frags
    //      4-way accumulator split: chains of 4 (vs 16) for 2-wave/SIMD ILP.
    f32x16 pa[4];
#pragma unroll
    for (int j = 0; j < 4; ++j)
#pragma unroll
      for (int e = 0; e < 16; ++e) pa[j][e] = 0.f;
    {
      const char* ub = (const char*)&Us[cur][0] + (size_t)(mt * 32 + lo) * 16 + hi * 1024;
      __builtin_amdgcn_s_setprio(1);
#pragma unroll
      for (int ks = 0; ks < 16; ++ks) {
        bf16x8 av = *(const bf16x8*)(ub + ks * 2048);
        pa[ks & 3] = __builtin_amdgcn_mfma_f32_32x32x16_bf16(av, xr[ks], pa[ks & 3], 0, 0, 0);
      }
      __builtin_amdgcn_s_setprio(0);
    }
    f32x16 pas = (pa[0] + pa[1]) + (pa[2] + pa[3]);

    // ---- gelu -> pack -> 4x ds_write_b64 (conflict-free linear)
    // pas[4g+e] = P[r=rtA*32+lo][m = mt*32 + g*8 + hi*4 + e]
#pragma unroll
    for (int g = 0; g < 4; ++g) {
      float gv[4];
#pragma unroll
      for (int e = 0; e < 4; ++e) {
        float v = pas[g * 4 + e];
        float p = __builtin_fmaf(0.1029433f, v * v, 2.3022082f);
        float ex = __builtin_amdgcn_exp2f(v * p);
        float r = __builtin_amdgcn_rcpf(ex + 1.0f);
        gv[e] = __builtin_fmaf(-v, r, v);
      }
      u32 w0, w1;
      asm("v_cvt_pk_bf16_f32 %0, %1, %2" : "=v"(w0) : "v"(gv[0]), "v"(gv[1]));
      asm("v_cvt_pk_bf16_f32 %0, %1, %2" : "=v"(w1) : "v"(gv[2]), "v"(gv[3]));
      uint2 pk; pk.x = w0; pk.y = w1;
      *(uint2*)(psW + (size_t)(mt * 4 + g) * 2048) = pk;
    }

    // barrier1: Ps handoff (DS only); staged loads NOT drained here
    __builtin_amdgcn_sched_barrier(0);
    asm volatile("s_waitcnt lgkmcnt(0)" ::: "memory");
    __builtin_amdgcn_s_barrier();
    __builtin_amdgcn_sched_barrier(0);

    // ---- phase B: C[64r x 64d] += Ps @ Down. Per ks: 2 A-frags (Ps) +
    //      2 B-frags (Ds, each reused x2) -> 4 MFMAs. All reads linear.
    {
      const char* dsb = (const char*)&Ds[cur][0];
      __builtin_amdgcn_s_setprio(1);
#pragma unroll
      for (int ks = 0; ks < 4; ++ks) {
        const size_t khp = (size_t)(ks * 2 + hi);
        bf16x8 a0 = *(const bf16x8*)(psB + khp * 2048 + (size_t)(rtp * 64 + lo) * 16);
        bf16x8 a1 = *(const bf16x8*)(psB + khp * 2048 + (size_t)(rtp * 64 + 32 + lo) * 16);
#pragma unroll
        for (int dt = 0; dt < 2; ++dt) {
          bf16x8 bv = *(const bf16x8*)(dsb + khp * 4096 + (size_t)(dq * 64 + dt * 32 + lo) * 16);
          ca[0][dt] = __builtin_amdgcn_mfma_f32_32x32x16_bf16(a0, bv, ca[0][dt], 0, 0, 0);
          ca[1][dt] = __builtin_amdgcn_mfma_f32_32x32x16_bf16(a1, bv, ca[1][dt], 0, 0, 0);
        }
      }
      __builtin_amdgcn_s_setprio(0);
    }

    // barrier2: Ps reads done; staged tiles landed (full-chunk cover)
    __syncthreads();
  }

  // ---- epilogue: out[b][h*256+d], coalesced across lanes (32 consecutive d)
  // C-layout 32x32: col d = lo, row = (reg&3) + 8*(reg>>2) + 4*hi.
  {
#pragma unroll
    for (int rt2 = 0; rt2 < 2; ++rt2)
#pragma unroll
      for (int dt = 0; dt < 2; ++dt) {
        const int d = h * ND + dq * 64 + dt * 32 + lo;
#pragma unroll
        for (int reg = 0; reg < 16; ++reg) {
          int r = rtp * 64 + rt2 * 32 + (reg & 3) + 8 * (reg >> 2) + 4 * hi;
          out[(size_t)(row0 + r) * 4096 + d] = ca[rt2][dt][reg];
        }
      }
  }
}

extern "C" void kernel_launch(void* const* d_in, const int* in_sizes, int n_in,
                              void* d_out, int out_size, void* d_ws, size_t ws_size,
                              hipStream_t stream) {
  const float* x    = (const float*)d_in[0];
  const float* up   = (const float*)d_in[1];
  const float* down = (const float*)d_in[2];
  const int* perm   = (const int*)d_in[3];
  const int* unperm = (const int*)d_in[4];
  float* out = (float*)d_out;

  u16* upF   = (u16*)d_ws;                                   // 8 MB
  u16* downF = upF + (size_t)NH * NM * ND;                   // 8 MB
  u16* xp    = downF + (size_t)NH * NM * ND;                 // 128 MB

  // weights -> fragment-granule order (one-time, coalesced tile transposes)
  prep_up<<<dim3(NM / 64, ND / 64, NH), 256, 0, stream>>>(up, upF);
  prep_down<<<dim3(NM / 64, ND / 64, NH), 256, 0, stream>>>(down, downF);
  // xp[b][i] = bf16(x[b][perm[i]])
  permute_x<<<NB, 1024, 0, stream>>>(x, perm, xp);
  // main fused MLP: 512 thr, 32x32x16 MFMA, linear staging, 144KB/CU.
  mlp_fused<<<dim3(NB / BM, NH), 512, 0, stream>>>(xp, upF, downF, out);
  // in-place feature unpermute
  unpermute_out<<<NB, 1024, 0, stream>>>(out, unperm);
}

// Round 9
// 615.701 us; speedup vs baseline: 1.2621x; 1.0131x over previous
//
#include <hip/hip_runtime.h>
#include <hip/hip_bf16.h>
#include <math.h>

#define NB 16384
#define NH 16
#define ND 256
#define NM 1024
#define BM 128           // rows per block
#define MB 64            // m-chunk
#define NCH (NM / MB)    // 16

typedef float f32x4 __attribute__((ext_vector_type(4)));
typedef float f32x16 __attribute__((ext_vector_type(16)));
typedef short bf16x8 __attribute__((ext_vector_type(8)));
typedef unsigned short u16;
typedef unsigned int u32;

__device__ __forceinline__ u16 f2bf(float f) {
  union { float f; unsigned u; } v; v.f = f;
  unsigned r = v.u + 0x7FFFu + ((v.u >> 16) & 1u);
  return (u16)(r >> 16);
}

// UpF[h]: granule byte off = mc*32768 + kh*1024 + m*16, kh in [0,32), m in [0,64)
//   elems e: up[h][kh*8+e][mc*64+m]   (up fp32 [H][256][1024])
__global__ __launch_bounds__(256) void prep_up(const float* __restrict__ src,
                                               u16* __restrict__ dst) {
  __shared__ float tile[64][65];
  const int h = blockIdx.z;
  const int m0 = blockIdx.x * 64, d0 = blockIdx.y * 64;
  const int tr = threadIdx.x >> 6, tc = threadIdx.x & 63;
  const float* s = src + (size_t)h * ND * NM;
#pragma unroll
  for (int i = 0; i < 16; ++i) {
    int r = i * 4 + tr;
    tile[r][tc] = s[(size_t)(d0 + r) * NM + m0 + tc];
  }
  __syncthreads();
  char* dh = (char*)dst + (size_t)h * NM * ND * 2;
#pragma unroll
  for (int g = 0; g < 2; ++g) {
    int gi = g * 256 + threadIdx.x;
    int kh_l = gi >> 6, m_l = gi & 63;
    bf16x8 o;
#pragma unroll
    for (int e = 0; e < 8; ++e) o[e] = (short)f2bf(tile[kh_l * 8 + e][m_l]);
    *(bf16x8*)(dh + (size_t)(m0 >> 6) * 32768 + (size_t)((d0 >> 3) + kh_l) * 1024 + m_l * 16) = o;
  }
}

// DownF[h]: granule byte off = mc*32768 + kh*4096 + d*16, kh in [0,8), d in [0,256)
//   elems e: down[h][mc*64+kh*8+e][d]   (down fp32 [H][1024][256])
__global__ __launch_bounds__(256) void prep_down(const float* __restrict__ src,
                                                 u16* __restrict__ dst) {
  __shared__ float tile[64][65];
  const int h = blockIdx.z;
  const int mc = blockIdx.x, d0 = blockIdx.y * 64;
  const int tr = threadIdx.x >> 6, tc = threadIdx.x & 63;
  const float* s = src + (size_t)h * NM * ND;
#pragma unroll
  for (int i = 0; i < 16; ++i) {
    int r = i * 4 + tr;
    tile[r][tc] = s[(size_t)(mc * 64 + r) * ND + d0 + tc];
  }
  __syncthreads();
  char* dh = (char*)dst + (size_t)h * NM * ND * 2;
#pragma unroll
  for (int g = 0; g < 2; ++g) {
    int gi = g * 256 + threadIdx.x;
    int kh_l = gi >> 6, d_l = gi & 63;
    bf16x8 o;
#pragma unroll
    for (int e = 0; e < 8; ++e) o[e] = (short)f2bf(tile[kh_l * 8 + e][d_l]);
    *(bf16x8*)(dh + (size_t)mc * 32768 + (size_t)kh_l * 4096 + (size_t)(d0 + d_l) * 16) = o;
  }
}

// xp[b][i] = bf16(x[b][perm[i]])
__global__ __launch_bounds__(1024) void permute_x(const float* __restrict__ x,
                                                  const int* __restrict__ perm,
                                                  u16* __restrict__ xp) {
  const int b = blockIdx.x;
  const int t = threadIdx.x;
  const float* xr = x + (size_t)b * 4096;
  int4 p = *(const int4*)(perm + t * 4);
  ushort4 o;
  o.x = f2bf(xr[p.x]); o.y = f2bf(xr[p.y]);
  o.z = f2bf(xr[p.z]); o.w = f2bf(xr[p.w]);
  *(ushort4*)(xp + (size_t)b * 4096 + t * 4) = o;
}

// out[b][j] = out[b][unperm[j]] (in place, one row per block)
__global__ __launch_bounds__(1024) void unpermute_out(float* __restrict__ out,
                                                      const int* __restrict__ unperm) {
  __shared__ float row[4096];
  const int b = blockIdx.x;
  const int t = threadIdx.x;
  float* orow = out + (size_t)b * 4096;
  *(f32x4*)(row + t * 4) = *(const f32x4*)(orow + t * 4);
  __syncthreads();
  int4 u = *(const int4*)(unperm + t * 4);
  f32x4 v;
  v.x = row[u.x]; v.y = row[u.y]; v.z = row[u.z]; v.w = row[u.w];
  *(f32x4*)(orow + t * 4) = v;
}

// 8-wave MLP, 32x32x16 MFMA, fragment-order LDS + R9: SINGLE-BARRIER
// software-pipelined region. R8's 2-barrier structure convoyed all 8 waves
// through homogeneous phases (reads-only / MFMA-only / GELU-only bursts:
// MfmaUtil 26%, VALU 28%, LDS ~45% -- all pipes <50%). Region i =
//   [issue stage_ds(i)+stage_us(i+1)] -> B(i-1) -> A(i) -> GELU->Ps[i&1]
//   -> lgkm0 + vmcnt0 + barrier
// Ps double-buffered (LDS 64+64+32 = 160KB exactly; AITER attn precedent).
// Within a region every staged buffer is disjoint from every read buffer;
// cross-region handoffs have exactly one barrier with per-wave vmcnt(0)
// issued a full region (~4000cy) after the loads -> drain is free.
__global__ __launch_bounds__(512, 2) void mlp_fused(
    const u16* __restrict__ xp,
    const u16* __restrict__ upF,
    const u16* __restrict__ downF,
    float* __restrict__ out) {
  __shared__ __align__(16) u16 Us[2][MB * ND];   // 2x32KB [kh32][m64][8]
  __shared__ __align__(16) u16 Ds[2][ND * MB];   // 2x32KB [kh8][d256][8]
  __shared__ __align__(16) u16 Ps[2][BM * MB];   // 2x16KB [kh8][r128][8]

  const int h   = blockIdx.y;
  const int rb  = blockIdx.x;
  const int tid = threadIdx.x;
  const int w   = tid >> 6;
  const int l   = tid & 63;
  const int lo  = l & 31;
  const int hi  = l >> 5;
  // phase-A mapping
  const int rtA = w & 3;      // 32-row tile
  const int mt  = w >> 2;     // 32-m tile of the 64-m chunk
  // phase-B mapping
  const int rtp = w & 1;      // 64-row half
  const int dq  = w >> 1;     // 64-d quarter
  const int row0 = rb * BM;

  const char* upH = (const char*)upF + (size_t)h * NM * ND * 2;
  const char* dnH = (const char*)downF + (size_t)h * NM * ND * 2;

  // ---- X fragments: phase-A B-operand. Lane = x-row (rtA*32+lo),
  //      k = ks*16 + hi*8 + e. 16 x b128 = 64 VGPR. (once per block)
  bf16x8 xr[16];
  {
    const char* px = (const char*)(xp + (size_t)(row0 + rtA * 32 + lo) * 4096 + h * ND);
#pragma unroll
    for (int ks = 0; ks < 16; ++ks)
      xr[ks] = *(const bf16x8*)(px + ks * 32 + hi * 16);
  }

  // ---- stage Up chunk 32KB: pure linear copy (fragment order on HBM)
  auto stage_us = [&](int mc, int buf) {
    const char* src = upH + (size_t)mc * 32768;
#pragma unroll
    for (int i = 0; i < 4; ++i) {
      int t = i * 512 + tid;
      __builtin_amdgcn_global_load_lds(
          (const __attribute__((address_space(1))) void*)(src + (size_t)t * 16),
          (__attribute__((address_space(3))) void*)((char*)&Us[buf][0] + (size_t)t * 16),
          16, 0, 0);
    }
  };
  // ---- stage Down chunk 32KB: pure linear copy
  auto stage_ds = [&](int mc, int buf) {
    const char* src = dnH + (size_t)mc * 32768;
#pragma unroll
    for (int i = 0; i < 4; ++i) {
      int t = i * 512 + tid;
      __builtin_amdgcn_global_load_lds(
          (const __attribute__((address_space(1))) void*)(src + (size_t)t * 16),
          (__attribute__((address_space(3))) void*)((char*)&Ds[buf][0] + (size_t)t * 16),
          16, 0, 0);
    }
  };

  f32x16 ca[2][2];   // [rt2][dt] 32x32 tiles: 64 rows x 64 d -> 64 VGPR
#pragma unroll
  for (int rt2 = 0; rt2 < 2; ++rt2)
#pragma unroll
    for (int dt = 0; dt < 2; ++dt)
#pragma unroll
      for (int e = 0; e < 16; ++e)
        ca[rt2][dt][e] = 0.f;

  // ---- prologue: publish Us(0)
  stage_us(0, 0);
  asm volatile("s_waitcnt vmcnt(0)" ::: "memory");
  __builtin_amdgcn_s_barrier();

  // Ps write base (buf 0): row r = rtA*32+lo, elem slot hi*8.
  char* const psW0 = (char*)&Ps[0][0] + (size_t)(rtA * 32 + lo) * 16 + hi * 8;

  for (int i = 0; i < NCH; ++i) {
    const int c = i & 1;
    // ---- region top: issue staging (disjoint from all buffers read below)
    stage_ds(i, c);                           // used by B(i) next region
    if (i + 1 < NCH) stage_us(i + 1, c ^ 1);  // used by A(i+1) next region

    // ---- phase B(i-1): C += Ps[c^1] @ Ds[c^1]  (skip for i=0)
    if (i > 0) {
      const char* psb = (const char*)&Ps[c ^ 1][0];
      const char* dsb = (const char*)&Ds[c ^ 1][0];
      __builtin_amdgcn_s_setprio(1);
#pragma unroll
      for (int ks = 0; ks < 4; ++ks) {
        const size_t khp = (size_t)(ks * 2 + hi);
        bf16x8 a0 = *(const bf16x8*)(psb + khp * 2048 + (size_t)(rtp * 64 + lo) * 16);
        bf16x8 a1 = *(const bf16x8*)(psb + khp * 2048 + (size_t)(rtp * 64 + 32 + lo) * 16);
#pragma unroll
        for (int dt = 0; dt < 2; ++dt) {
          bf16x8 bv = *(const bf16x8*)(dsb + khp * 4096 + (size_t)(dq * 64 + dt * 32 + lo) * 16);
          ca[0][dt] = __builtin_amdgcn_mfma_f32_32x32x16_bf16(a0, bv, ca[0][dt], 0, 0, 0);
          ca[1][dt] = __builtin_amdgcn_mfma_f32_32x32x16_bf16(a1, bv, ca[1][dt], 0, 0, 0);
        }
      }
      __builtin_amdgcn_s_setprio(0);
    }

    // ---- phase A(i) (swapped): P^T[32m x 32r] = Up-frags @ X-frags
    f32x16 pa[4];
#pragma unroll
    for (int j = 0; j < 4; ++j)
#pragma unroll
      for (int e = 0; e < 16; ++e) pa[j][e] = 0.f;
    {
      const char* ub = (const char*)&Us[c][0] + (size_t)(mt * 32 + lo) * 16 + hi * 1024;
      __builtin_amdgcn_s_setprio(1);
#pragma unroll
      for (int ks = 0; ks < 16; ++ks) {
        bf16x8 av = *(const bf16x8*)(ub + ks * 2048);
        pa[ks & 3] = __builtin_amdgcn_mfma_f32_32x32x16_bf16(av, xr[ks], pa[ks & 3], 0, 0, 0);
      }
      __builtin_amdgcn_s_setprio(0);
    }
    f32x16 pas = (pa[0] + pa[1]) + (pa[2] + pa[3]);

    // ---- gelu -> pack -> 4x ds_write_b64 into Ps[c] (conflict-free linear)
#pragma unroll
    for (int g = 0; g < 4; ++g) {
      float gv[4];
#pragma unroll
      for (int e = 0; e < 4; ++e) {
        float v = pas[g * 4 + e];
        float p = __builtin_fmaf(0.1029433f, v * v, 2.3022082f);
        float ex = __builtin_amdgcn_exp2f(v * p);
        float r = __builtin_amdgcn_rcpf(ex + 1.0f);
        gv[e] = __builtin_fmaf(-v, r, v);
      }
      u32 w0, w1;
      asm("v_cvt_pk_bf16_f32 %0, %1, %2" : "=v"(w0) : "v"(gv[0]), "v"(gv[1]));
      asm("v_cvt_pk_bf16_f32 %0, %1, %2" : "=v"(w1) : "v"(gv[2]), "v"(gv[3]));
      uint2 pk; pk.x = w0; pk.y = w1;
      *(uint2*)(psW0 + (size_t)c * (BM * MB * 2) + (size_t)(mt * 4 + g) * 2048) = pk;
    }

    // ---- region end: publish Ps[c] (lgkm) + Ds(i)/Us(i+1) (vmem, issued
    //      ~a full region ago -> drain free) then ONE barrier.
    asm volatile("s_waitcnt lgkmcnt(0)" ::: "memory");
    asm volatile("s_waitcnt vmcnt(0)" ::: "memory");
    __builtin_amdgcn_s_barrier();
  }

  // ---- epilogue phase B(NCH-1): Ps[1], Ds[1]
  {
    const int c = (NCH - 1) & 1;
    const char* psb = (const char*)&Ps[c][0];
    const char* dsb = (const char*)&Ds[c][0];
    __builtin_amdgcn_s_setprio(1);
#pragma unroll
    for (int ks = 0; ks < 4; ++ks) {
      const size_t khp = (size_t)(ks * 2 + hi);
      bf16x8 a0 = *(const bf16x8*)(psb + khp * 2048 + (size_t)(rtp * 64 + lo) * 16);
      bf16x8 a1 = *(const bf16x8*)(psb + khp * 2048 + (size_t)(rtp * 64 + 32 + lo) * 16);
#pragma unroll
      for (int dt = 0; dt < 2; ++dt) {
        bf16x8 bv = *(const bf16x8*)(dsb + khp * 4096 + (size_t)(dq * 64 + dt * 32 + lo) * 16);
        ca[0][dt] = __builtin_amdgcn_mfma_f32_32x32x16_bf16(a0, bv, ca[0][dt], 0, 0, 0);
        ca[1][dt] = __builtin_amdgcn_mfma_f32_32x32x16_bf16(a1, bv, ca[1][dt], 0, 0, 0);
      }
    }
    __builtin_amdgcn_s_setprio(0);
  }

  // ---- epilogue: out[b][h*256+d], coalesced across lanes (32 consecutive d)
  // C-layout 32x32: col d = lo, row = (reg&3) + 8*(reg>>2) + 4*hi.
  {
#pragma unroll
    for (int rt2 = 0; rt2 < 2; ++rt2)
#pragma unroll
      for (int dt = 0; dt < 2; ++dt) {
        const int d = h * ND + dq * 64 + dt * 32 + lo;
#pragma unroll
        for (int reg = 0; reg < 16; ++reg) {
          int r = rtp * 64 + rt2 * 32 + (reg & 3) + 8 * (reg >> 2) + 4 * hi;
          out[(size_t)(row0 + r) * 4096 + d] = ca[rt2][dt][reg];
        }
      }
  }
}

extern "C" void kernel_launch(void* const* d_in, const int* in_sizes, int n_in,
                              void* d_out, int out_size, void* d_ws, size_t ws_size,
                              hipStream_t stream) {
  const float* x    = (const float*)d_in[0];
  const float* up   = (const float*)d_in[1];
  const float* down = (const float*)d_in[2];
  const int* perm   = (const int*)d_in[3];
  const int* unperm = (const int*)d_in[4];
  float* out = (float*)d_out;

  u16* upF   = (u16*)d_ws;                                   // 8 MB
  u16* downF = upF + (size_t)NH * NM * ND;                   // 8 MB
  u16* xp    = downF + (size_t)NH * NM * ND;                 // 128 MB

  // weights -> fragment-granule order (one-time, coalesced tile transposes)
  prep_up<<<dim3(NM / 64, ND / 64, NH), 256, 0, stream>>>(up, upF);
  prep_down<<<dim3(NM / 64, ND / 64, NH), 256, 0, stream>>>(down, downF);
  // xp[b][i] = bf16(x[b][perm[i]])
  permute_x<<<NB, 1024, 0, stream>>>(x, perm, xp);
  // main fused MLP: 512 thr, 32x32x16 MFMA, single-barrier pipeline, 160KB.
  mlp_fused<<<dim3(NB / BM, NH), 512, 0, stream>>>(xp, upF, downF, out);
  // in-place feature unpermute
  unpermute_out<<<NB, 1024, 0, stream>>>(out, unperm);
}

// Round 10
// 559.979 us; speedup vs baseline: 1.3877x; 1.0995x over previous
//
#include <hip/hip_runtime.h>
#include <hip/hip_bf16.h>
#include <math.h>

#define NB 16384
#define NH 16
#define ND 256
#define NM 1024
#define BM 128           // rows per block
#define MB 64            // m-chunk
#define NCH (NM / MB)    // 16

typedef float f32x4 __attribute__((ext_vector_type(4)));
typedef float f32x16 __attribute__((ext_vector_type(16)));
typedef short bf16x8 __attribute__((ext_vector_type(8)));
typedef unsigned short u16;
typedef unsigned int u32;

__device__ __forceinline__ u16 f2bf(float f) {
  union { float f; unsigned u; } v; v.f = f;
  unsigned r = v.u + 0x7FFFu + ((v.u >> 16) & 1u);
  return (u16)(r >> 16);
}

// UpF[h]: granule byte off = mc*32768 + kh*1024 + m*16, kh in [0,32), m in [0,64)
//   elems e: up[h][kh*8+e][mc*64+m]   (up fp32 [H][256][1024])
__global__ __launch_bounds__(256) void prep_up(const float* __restrict__ src,
                                               u16* __restrict__ dst) {
  __shared__ float tile[64][65];
  const int h = blockIdx.z;
  const int m0 = blockIdx.x * 64, d0 = blockIdx.y * 64;
  const int tr = threadIdx.x >> 6, tc = threadIdx.x & 63;
  const float* s = src + (size_t)h * ND * NM;
#pragma unroll
  for (int i = 0; i < 16; ++i) {
    int r = i * 4 + tr;
    tile[r][tc] = s[(size_t)(d0 + r) * NM + m0 + tc];
  }
  __syncthreads();
  char* dh = (char*)dst + (size_t)h * NM * ND * 2;
#pragma unroll
  for (int g = 0; g < 2; ++g) {
    int gi = g * 256 + threadIdx.x;
    int kh_l = gi >> 6, m_l = gi & 63;
    bf16x8 o;
#pragma unroll
    for (int e = 0; e < 8; ++e) o[e] = (short)f2bf(tile[kh_l * 8 + e][m_l]);
    *(bf16x8*)(dh + (size_t)(m0 >> 6) * 32768 + (size_t)((d0 >> 3) + kh_l) * 1024 + m_l * 16) = o;
  }
}

// DownF[h]: granule byte off = mc*32768 + kh*4096 + d*16, kh in [0,8), d in [0,256)
//   elems e: down[h][mc*64+kh*8+e][d]   (down fp32 [H][1024][256])
__global__ __launch_bounds__(256) void prep_down(const float* __restrict__ src,
                                                 u16* __restrict__ dst) {
  __shared__ float tile[64][65];
  const int h = blockIdx.z;
  const int mc = blockIdx.x, d0 = blockIdx.y * 64;
  const int tr = threadIdx.x >> 6, tc = threadIdx.x & 63;
  const float* s = src + (size_t)h * NM * ND;
#pragma unroll
  for (int i = 0; i < 16; ++i) {
    int r = i * 4 + tr;
    tile[r][tc] = s[(size_t)(mc * 64 + r) * ND + d0 + tc];
  }
  __syncthreads();
  char* dh = (char*)dst + (size_t)h * NM * ND * 2;
#pragma unroll
  for (int g = 0; g < 2; ++g) {
    int gi = g * 256 + threadIdx.x;
    int kh_l = gi >> 6, d_l = gi & 63;
    bf16x8 o;
#pragma unroll
    for (int e = 0; e < 8; ++e) o[e] = (short)f2bf(tile[kh_l * 8 + e][d_l]);
    *(bf16x8*)(dh + (size_t)mc * 32768 + (size_t)kh_l * 4096 + (size_t)(d0 + d_l) * 16) = o;
  }
}

// xp[b][i] = bf16(x[b][perm[i]])
__global__ __launch_bounds__(1024) void permute_x(const float* __restrict__ x,
                                                  const int* __restrict__ perm,
                                                  u16* __restrict__ xp) {
  const int b = blockIdx.x;
  const int t = threadIdx.x;
  const float* xr = x + (size_t)b * 4096;
  int4 p = *(const int4*)(perm + t * 4);
  ushort4 o;
  o.x = f2bf(xr[p.x]); o.y = f2bf(xr[p.y]);
  o.z = f2bf(xr[p.z]); o.w = f2bf(xr[p.w]);
  *(ushort4*)(xp + (size_t)b * 4096 + t * 4) = o;
}

// out[b][j] = out[b][unperm[j]] (in place, one row per block)
__global__ __launch_bounds__(1024) void unpermute_out(float* __restrict__ out,
                                                      const int* __restrict__ unperm) {
  __shared__ float row[4096];
  const int b = blockIdx.x;
  const int t = threadIdx.x;
  float* orow = out + (size_t)b * 4096;
  *(f32x4*)(row + t * 4) = *(const f32x4*)(orow + t * 4);
  __syncthreads();
  int4 u = *(const int4*)(unperm + t * 4);
  f32x4 v;
  v.x = row[u.x]; v.y = row[u.y]; v.z = row[u.z]; v.w = row[u.w];
  *(f32x4*)(orow + t * 4) = v;
}

// 16-wave PRODUCER/CONSUMER MLP. R9 showed all pipes <50% at 2 waves/SIMD
// (TLP starvation; homogeneous waves can't exceed 2/SIMD without spilling
// the ~190-reg combined working set). Split roles:
//   A-waves (w<8): xr[16](64) + pa(16) -> up-proj MFMAs + GELU -> Ps[i&1]
//   B-waves (w>=8): ca[2][2](64) -> down-proj MFMAs from Ps/Ds[(i-1)&1]
// Each role's registers live only in its own top-level branch+loop -> the
// allocator overlays them: max ~116 VGPR <= 128 cap of (1024,4) -> 4
// waves/SIMD (2A+2B): A-chains, B-chains, GELU VALU and staging co-schedule.
// Region i: A{stage Us(i+1,c^1); A(i) from Us[c]; GELU->Ps[c]} ||
//           B{stage Ds(i,c); if i>0 B(i-1) from Ps[c^1],Ds[c^1]}
//           -> per-branch waitcnt + ONE barrier (equal count both branches).
// Parity: all staged buffers disjoint from all read buffers in-region;
// every handoff crosses exactly one barrier with drain before it.
__global__ __launch_bounds__(1024, 4) void mlp_fused(
    const u16* __restrict__ xp,
    const u16* __restrict__ upF,
    const u16* __restrict__ downF,
    float* __restrict__ out) {
  __shared__ __align__(16) u16 Us[2][MB * ND];   // 2x32KB [kh32][m64][8]
  __shared__ __align__(16) u16 Ds[2][ND * MB];   // 2x32KB [kh8][d256][8]
  __shared__ __align__(16) u16 Ps[2][BM * MB];   // 2x16KB [kh8][r128][8]

  const int h   = blockIdx.y;
  const int rb  = blockIdx.x;
  const int tid = threadIdx.x;
  const int w   = tid >> 6;
  const int l   = tid & 63;
  const int lo  = l & 31;
  const int hi  = l >> 5;
  const int row0 = rb * BM;

  const char* upH = (const char*)upF + (size_t)h * NM * ND * 2;
  const char* dnH = (const char*)downF + (size_t)h * NM * ND * 2;

  // ---- prologue: all 16 waves stage Us(0) (2 insts/thread), then barrier
  {
#pragma unroll
    for (int i = 0; i < 2; ++i) {
      int t = i * 1024 + tid;
      __builtin_amdgcn_global_load_lds(
          (const __attribute__((address_space(1))) void*)(upH + (size_t)t * 16),
          (__attribute__((address_space(3))) void*)((char*)&Us[0][0] + (size_t)t * 16),
          16, 0, 0);
    }
  }
  asm volatile("s_waitcnt vmcnt(0)" ::: "memory");
  __builtin_amdgcn_s_barrier();

  if (w < 8) {
    // ================= producer (A) =================
    const int rtA = w & 3;    // 32-row tile
    const int mt  = w >> 2;   // 32-m tile of the 64-m chunk

    // X fragments: lane = x-row (rtA*32+lo), k = ks*16 + hi*8 + e. 64 VGPR.
    bf16x8 xr[16];
    {
      const char* px = (const char*)(xp + (size_t)(row0 + rtA * 32 + lo) * 4096 + h * ND);
#pragma unroll
      for (int ks = 0; ks < 16; ++ks)
        xr[ks] = *(const bf16x8*)(px + ks * 32 + hi * 16);
    }
    char* const psW = (char*)&Ps[0][0] + (size_t)(rtA * 32 + lo) * 16 + hi * 8;

    for (int i = 0; i < NCH; ++i) {
      const int c = i & 1;
      // stage Us(i+1) -> buf c^1 (A-threads: tid in [0,512), 4 insts)
      if (i + 1 < NCH) {
        const char* src = upH + (size_t)(i + 1) * 32768;
#pragma unroll
        for (int j = 0; j < 4; ++j) {
          int t = j * 512 + tid;
          __builtin_amdgcn_global_load_lds(
              (const __attribute__((address_space(1))) void*)(src + (size_t)t * 16),
              (__attribute__((address_space(3))) void*)((char*)&Us[c ^ 1][0] + (size_t)t * 16),
              16, 0, 0);
        }
      }

      // A(i): P^T[32m x 32r] = Up-frags @ X-frags (single chain-16; 2A+2B
      // waves/SIMD keep the pipe fed)
      f32x16 pa;
#pragma unroll
      for (int e = 0; e < 16; ++e) pa[e] = 0.f;
      {
        const char* ub = (const char*)&Us[c][0] + (size_t)(mt * 32 + lo) * 16 + hi * 1024;
        __builtin_amdgcn_s_setprio(1);
#pragma unroll
        for (int ks = 0; ks < 16; ++ks) {
          bf16x8 av = *(const bf16x8*)(ub + ks * 2048);
          pa = __builtin_amdgcn_mfma_f32_32x32x16_bf16(av, xr[ks], pa, 0, 0, 0);
        }
        __builtin_amdgcn_s_setprio(0);
      }

      // gelu -> pack -> 4x ds_write_b64 into Ps[c]
      // pa[4g+e] = P[r=rtA*32+lo][m = mt*32 + g*8 + hi*4 + e]
#pragma unroll
      for (int g = 0; g < 4; ++g) {
        float gv[4];
#pragma unroll
        for (int e = 0; e < 4; ++e) {
          float v = pa[g * 4 + e];
          float p = __builtin_fmaf(0.1029433f, v * v, 2.3022082f);
          float ex = __builtin_amdgcn_exp2f(v * p);
          float r = __builtin_amdgcn_rcpf(ex + 1.0f);
          gv[e] = __builtin_fmaf(-v, r, v);
        }
        u32 w0, w1;
        asm("v_cvt_pk_bf16_f32 %0, %1, %2" : "=v"(w0) : "v"(gv[0]), "v"(gv[1]));
        asm("v_cvt_pk_bf16_f32 %0, %1, %2" : "=v"(w1) : "v"(gv[2]), "v"(gv[3]));
        uint2 pk; pk.x = w0; pk.y = w1;
        *(uint2*)(psW + (size_t)c * (BM * MB * 2) + (size_t)(mt * 4 + g) * 2048) = pk;
      }

      __builtin_amdgcn_sched_barrier(0);
      asm volatile("s_waitcnt lgkmcnt(0)" ::: "memory");   // Ps published
      asm volatile("s_waitcnt vmcnt(0)" ::: "memory");     // Us(i+1) landed
      __builtin_amdgcn_s_barrier();
      __builtin_amdgcn_sched_barrier(0);
    }
    // A-waves done (out written by B-waves)
  } else {
    // ================= consumer (B) =================
    const int wb  = w - 8;
    const int rtp = wb & 1;   // 64-row half
    const int dq  = wb >> 1;  // 64-d quarter
    const int tb  = tid - 512;

    f32x16 ca[2][2];   // [rt2][dt] 32x32 tiles: 64r x 64d -> 64 VGPR
#pragma unroll
    for (int rt2 = 0; rt2 < 2; ++rt2)
#pragma unroll
      for (int dt = 0; dt < 2; ++dt)
#pragma unroll
        for (int e = 0; e < 16; ++e)
          ca[rt2][dt][e] = 0.f;

    for (int i = 0; i < NCH; ++i) {
      const int c = i & 1;
      // stage Ds(i) -> buf c (B-threads, 4 insts)
      {
        const char* src = dnH + (size_t)i * 32768;
#pragma unroll
        for (int j = 0; j < 4; ++j) {
          int t = j * 512 + tb;
          __builtin_amdgcn_global_load_lds(
              (const __attribute__((address_space(1))) void*)(src + (size_t)t * 16),
              (__attribute__((address_space(3))) void*)((char*)&Ds[c][0] + (size_t)t * 16),
              16, 0, 0);
        }
      }

      // B(i-1): C += Ps[c^1] @ Ds[c^1]
      if (i > 0) {
        const char* psb = (const char*)&Ps[c ^ 1][0];
        const char* dsb = (const char*)&Ds[c ^ 1][0];
        __builtin_amdgcn_s_setprio(1);
#pragma unroll
        for (int ks = 0; ks < 4; ++ks) {
          const size_t khp = (size_t)(ks * 2 + hi);
          bf16x8 a0 = *(const bf16x8*)(psb + khp * 2048 + (size_t)(rtp * 64 + lo) * 16);
          bf16x8 a1 = *(const bf16x8*)(psb + khp * 2048 + (size_t)(rtp * 64 + 32 + lo) * 16);
#pragma unroll
          for (int dt = 0; dt < 2; ++dt) {
            bf16x8 bv = *(const bf16x8*)(dsb + khp * 4096 + (size_t)(dq * 64 + dt * 32 + lo) * 16);
            ca[0][dt] = __builtin_amdgcn_mfma_f32_32x32x16_bf16(a0, bv, ca[0][dt], 0, 0, 0);
            ca[1][dt] = __builtin_amdgcn_mfma_f32_32x32x16_bf16(a1, bv, ca[1][dt], 0, 0, 0);
          }
        }
        __builtin_amdgcn_s_setprio(0);
      }

      __builtin_amdgcn_sched_barrier(0);
      asm volatile("s_waitcnt vmcnt(0)" ::: "memory");     // Ds(i) landed
      __builtin_amdgcn_s_barrier();
      __builtin_amdgcn_sched_barrier(0);
    }

    // final B(NCH-1): Ps[1], Ds[1]
    {
      const int c = (NCH - 1) & 1;
      const char* psb = (const char*)&Ps[c][0];
      const char* dsb = (const char*)&Ds[c][0];
      __builtin_amdgcn_s_setprio(1);
#pragma unroll
      for (int ks = 0; ks < 4; ++ks) {
        const size_t khp = (size_t)(ks * 2 + hi);
        bf16x8 a0 = *(const bf16x8*)(psb + khp * 2048 + (size_t)(rtp * 64 + lo) * 16);
        bf16x8 a1 = *(const bf16x8*)(psb + khp * 2048 + (size_t)(rtp * 64 + 32 + lo) * 16);
#pragma unroll
        for (int dt = 0; dt < 2; ++dt) {
          bf16x8 bv = *(const bf16x8*)(dsb + khp * 4096 + (size_t)(dq * 64 + dt * 32 + lo) * 16);
          ca[0][dt] = __builtin_amdgcn_mfma_f32_32x32x16_bf16(a0, bv, ca[0][dt], 0, 0, 0);
          ca[1][dt] = __builtin_amdgcn_mfma_f32_32x32x16_bf16(a1, bv, ca[1][dt], 0, 0, 0);
        }
      }
      __builtin_amdgcn_s_setprio(0);
    }

    // epilogue: out[b][h*256+d], coalesced across lanes (32 consecutive d)
    // C-layout 32x32: col d = lo, row = (reg&3) + 8*(reg>>2) + 4*hi.
#pragma unroll
    for (int rt2 = 0; rt2 < 2; ++rt2)
#pragma unroll
      for (int dt = 0; dt < 2; ++dt) {
        const int d = h * ND + dq * 64 + dt * 32 + lo;
#pragma unroll
        for (int reg = 0; reg < 16; ++reg) {
          int r = rtp * 64 + rt2 * 32 + (reg & 3) + 8 * (reg >> 2) + 4 * hi;
          out[(size_t)(row0 + r) * 4096 + d] = ca[rt2][dt][reg];
        }
      }
  }
}

extern "C" void kernel_launch(void* const* d_in, const int* in_sizes, int n_in,
                              void* d_out, int out_size, void* d_ws, size_t ws_size,
                              hipStream_t stream) {
  const float* x    = (const float*)d_in[0];
  const float* up   = (const float*)d_in[1];
  const float* down = (const float*)d_in[2];
  const int* perm   = (const int*)d_in[3];
  const int* unperm = (const int*)d_in[4];
  float* out = (float*)d_out;

  u16* upF   = (u16*)d_ws;                                   // 8 MB
  u16* downF = upF + (size_t)NH * NM * ND;                   // 8 MB
  u16* xp    = downF + (size_t)NH * NM * ND;                 // 128 MB

  // weights -> fragment-granule order (one-time, coalesced tile transposes)
  prep_up<<<dim3(NM / 64, ND / 64, NH), 256, 0, stream>>>(up, upF);
  prep_down<<<dim3(NM / 64, ND / 64, NH), 256, 0, stream>>>(down, downF);
  // xp[b][i] = bf16(x[b][perm[i]])
  permute_x<<<NB, 1024, 0, stream>>>(x, perm, xp);
  // main fused MLP: 1024 thr (8 producer + 8 consumer waves), 160KB LDS.
  mlp_fused<<<dim3(NB / BM, NH), 1024, 0, stream>>>(xp, upF, downF, out);
  // in-place feature unpermute
  unpermute_out<<<NB, 1024, 0, stream>>>(out, unperm);
}